// Round 29
// baseline (139.914 us; speedup 1.0000x reference)
//
#include <hip/hip_runtime.h>
#include <stdint.h>

// H-maxima: 128 iters of m = min(dilate3x3(m), img), marker0 = img - h.
// SINGLE LAUNCH, TWO GENERATIONS PER BARRIER:
// 128 blocks (1/image) x 512 thr = 32 groups x 16 segs, 8 rows/thread
// (all 256 rows in registers). Per step: exchange 2-row halo (parity A/B
// [2][32][256] each = 128 KiB total), one barrier, compute gen t+1 on 10
// rows (halo rows -1/+8 use mask regs ka/kb loaded once -- masks invariant),
// then gen t+2 on the 8 owned rows. 64 steps = 128 gens.
// Exit flags (3-slot rotation) + per-group chg skip (exact: inputs are only
// G-1,G,G+1) carried from R25/R28, incl. merged flag+act loads, seg0 writes.

#define NEGPAIR 0xFBFFFBFFu   // fp16 -65504 x2 == -inf pad
#define STEPS 64
#define GROUPS 32

typedef _Float16 h2  __attribute__((ext_vector_type(2)));
typedef __fp16   fh2 __attribute__((ext_vector_type(2)));

static __device__ __forceinline__ uint32_t pmax(uint32_t a, uint32_t b) {
    uint32_t r;
    asm("v_pk_max_f16 %0, %1, %2" : "=v"(r) : "v"(a), "v"(b));
    return r;
}
static __device__ __forceinline__ uint32_t pmin(uint32_t a, uint32_t b) {
    uint32_t r;
    asm("v_pk_min_f16 %0, %1, %2" : "=v"(r) : "v"(a), "v"(b));
    return r;
}
static __device__ __forceinline__ uint32_t alignb(uint32_t hi, uint32_t lo) {
    return __builtin_amdgcn_alignbit(hi, lo, 16);   // {lo.hi16, hi.lo16}
}
static __device__ __forceinline__ uint32_t pack2(float lo, float hi) {
    fh2 p = __builtin_amdgcn_cvt_pkrtz(lo, hi);
    return __builtin_bit_cast(uint32_t, p);
}
// seg s gets seg s-1's word; seg 0 gets NEGPAIR (16-lane DPP row == seg group)
static __device__ __forceinline__ uint32_t dpp_shr1(uint32_t s) {
    return (uint32_t)__builtin_amdgcn_update_dpp((int)NEGPAIR, (int)s, 0x111, 0xF, 0xF, false);
}
// seg s gets seg s+1's word; seg 15 gets NEGPAIR
static __device__ __forceinline__ uint32_t dpp_shl1(uint32_t s) {
    return (uint32_t)__builtin_amdgcn_update_dpp((int)NEGPAIR, (int)s, 0x101, 0xF, 0xF, false);
}

struct W8 { uint32_t s0, s1, s2, s3, s4, s5, s6, s7; };

static __device__ __forceinline__ W8 ld8(const uint32_t* p) {
    uint4 a = reinterpret_cast<const uint4*>(p)[0];
    uint4 b = reinterpret_cast<const uint4*>(p)[1];
    W8 w;
    w.s0 = a.x; w.s1 = a.y; w.s2 = a.z; w.s3 = a.w;
    w.s4 = b.x; w.s5 = b.y; w.s6 = b.z; w.s7 = b.w;
    return w;
}
static __device__ __forceinline__ void st8(uint32_t* p, W8 w) {
    reinterpret_cast<uint4*>(p)[0] = make_uint4(w.s0, w.s1, w.s2, w.s3);
    reinterpret_cast<uint4*>(p)[1] = make_uint4(w.s4, w.s5, w.s6, w.s7);
}
static __device__ __forceinline__ W8 wmax(W8 a, W8 b) {
    W8 r;
    r.s0 = pmax(a.s0, b.s0); r.s1 = pmax(a.s1, b.s1);
    r.s2 = pmax(a.s2, b.s2); r.s3 = pmax(a.s3, b.s3);
    r.s4 = pmax(a.s4, b.s4); r.s5 = pmax(a.s5, b.s5);
    r.s6 = pmax(a.s6, b.s6); r.s7 = pmax(a.s7, b.s7);
    return r;
}
static __device__ __forceinline__ W8 wneg() {
    W8 r;
    r.s0 = NEGPAIR; r.s1 = NEGPAIR; r.s2 = NEGPAIR; r.s3 = NEGPAIR;
    r.s4 = NEGPAIR; r.s5 = NEGPAIR; r.s6 = NEGPAIR; r.s7 = NEGPAIR;
    return r;
}
static __device__ __forceinline__ uint32_t wdiff(W8 a, W8 b) {
    return (a.s0 ^ b.s0) | (a.s1 ^ b.s1) | (a.s2 ^ b.s2) | (a.s3 ^ b.s3) |
           (a.s4 ^ b.s4) | (a.s5 ^ b.s5) | (a.s6 ^ b.s6) | (a.s7 ^ b.s7);
}

// horizontal 3-tap max on packed row v, clamped by k: min(hmax3(v), k)
static __device__ __forceinline__ W8 hpass(W8 v, W8 k) {
    uint32_t lv = dpp_shr1(v.s7);
    uint32_t rv = dpp_shl1(v.s0);
    W8 m;
    m.s0 = pmin(pmax(pmax(v.s0, alignb(v.s0, lv)),   alignb(v.s1, v.s0)), k.s0);
    m.s1 = pmin(pmax(pmax(v.s1, alignb(v.s1, v.s0)), alignb(v.s2, v.s1)), k.s1);
    m.s2 = pmin(pmax(pmax(v.s2, alignb(v.s2, v.s1)), alignb(v.s3, v.s2)), k.s2);
    m.s3 = pmin(pmax(pmax(v.s3, alignb(v.s3, v.s2)), alignb(v.s4, v.s3)), k.s3);
    m.s4 = pmin(pmax(pmax(v.s4, alignb(v.s4, v.s3)), alignb(v.s5, v.s4)), k.s4);
    m.s5 = pmin(pmax(pmax(v.s5, alignb(v.s5, v.s4)), alignb(v.s6, v.s5)), k.s5);
    m.s6 = pmin(pmax(pmax(v.s6, alignb(v.s6, v.s5)), alignb(v.s7, v.s6)), k.s6);
    m.s7 = pmin(pmax(pmax(v.s7, alignb(v.s7, v.s6)), alignb(rv,   v.s7)), k.s7);
    return m;
}

// load one image row (b, ir), seg's 16 px, as packed fp16 pair-of-quads
static __device__ __forceinline__ W8 ldrow_f32(const float* img, int b, int ir, int seg) {
    const float4* src = reinterpret_cast<const float4*>(
        img + ((size_t)b << 16) + ((size_t)ir << 8) + seg * 16);
    float4 fa = src[0], fb = src[1], fc = src[2], fd = src[3];
    W8 w;
    w.s0 = pack2(fa.x, fa.y); w.s1 = pack2(fa.z, fa.w);
    w.s2 = pack2(fb.x, fb.y); w.s3 = pack2(fb.z, fb.w);
    w.s4 = pack2(fc.x, fc.y); w.s5 = pack2(fc.z, fc.w);
    w.s6 = pack2(fd.x, fd.y); w.s7 = pack2(fd.z, fd.w);
    return w;
}

__global__ __launch_bounds__(512, 2) void hx_full(
    const float* __restrict__ img,   // f32 [128][256][256]
    const float* __restrict__ hh,    // f32 [128]
    float*       __restrict__ fout)  // f32 out
{
    // A[p][G]: G's rows m6 ([0..128)), m7 ([128..256)) -- read by G+1.
    // B[p][G]: G's rows m0, m1 -- read by G-1.
    // Dead rows B[p][0], A[p][31] host exit-flag slots (word 0) and chg
    // bitmaps (A[p][31][8..42)).
    __shared__ uint32_t A[2][GROUPS][256];   // 65,536 B
    __shared__ uint32_t B[2][GROUPS][256];   // 65,536 B (total exactly 128 KiB)

    const int tid = threadIdx.x;
    const int seg = tid & 15;
    const int G   = tid >> 4;        // 32 groups x 8 rows = 256 rows
    const int b   = blockIdx.x;      // one image per block
    const int sw  = seg * 8;

    uint32_t* f0p = &B[0][0][0];
    uint32_t* f1p = &B[1][0][0];
    uint32_t* f2p = &A[0][GROUPS - 1][0];
    uint32_t* cg0 = &A[0][GROUPS - 1][8];   // chg parity 0: entries [0..34)
    uint32_t* cg1 = &A[1][GROUPS - 1][8];   // chg parity 1
    if (tid == 0) { *f0p = 0; *f1p = 0; *f2p = 0; }
    if (tid < 34) {                         // pads 0,33 = 0; groups = 1
        uint32_t v = (tid >= 1 && tid <= 32) ? 1u : 0u;
        cg0[tid] = v; cg1[tid] = v;
    }
    uint32_t *pW = f0p, *pR = f2p, *pZ = f1p;  // s=0: write s0, read s2, reset s1

    // Fused init: rows 8G..8G+7 (always in-range) + halo-row masks ka/kb.
    W8 m0,m1,m2,m3,m4,m5,m6,m7, k0,k1,k2,k3,k4,k5,k6,k7, ka,kb;
    const float hb = hh[b];
    {
        const int r0 = 8 * G;
        k0 = ldrow_f32(img, b, r0+0, seg); k1 = ldrow_f32(img, b, r0+1, seg);
        k2 = ldrow_f32(img, b, r0+2, seg); k3 = ldrow_f32(img, b, r0+3, seg);
        k4 = ldrow_f32(img, b, r0+4, seg); k5 = ldrow_f32(img, b, r0+5, seg);
        k6 = ldrow_f32(img, b, r0+6, seg); k7 = ldrow_f32(img, b, r0+7, seg);
        ka = (G > 0)          ? ldrow_f32(img, b, r0 - 1, seg) : wneg();
        kb = (G < GROUPS - 1) ? ldrow_f32(img, b, r0 + 8, seg) : wneg();
        const uint32_t hp = pack2(hb, hb);
        // marker = img - h, done in packed domain: m = k - h (fp16 sub)
        // (match reference rounding: compute in f32 then pack)
        const float4* src = reinterpret_cast<const float4*>(
            img + ((size_t)b << 16) + ((size_t)r0 << 8) + seg * 16);
        (void)hp; (void)src;
        #pragma unroll
        for (int r = 0; r < 8; ++r) {
            const float4* s2 = reinterpret_cast<const float4*>(
                img + ((size_t)b << 16) + ((size_t)(r0 + r) << 8) + seg * 16);
            float4 fa = s2[0], fb2 = s2[1], fc = s2[2], fd = s2[3];
            W8 mv;
            mv.s0 = pack2(fa.x-hb, fa.y-hb);  mv.s1 = pack2(fa.z-hb, fa.w-hb);
            mv.s2 = pack2(fb2.x-hb, fb2.y-hb); mv.s3 = pack2(fb2.z-hb, fb2.w-hb);
            mv.s4 = pack2(fc.x-hb, fc.y-hb);  mv.s5 = pack2(fc.z-hb, fc.w-hb);
            mv.s6 = pack2(fd.x-hb, fd.y-hb);  mv.s7 = pack2(fd.z-hb, fd.w-hb);
            if (r == 0) m0 = mv; else if (r == 1) m1 = mv;
            else if (r == 2) m2 = mv; else if (r == 3) m3 = mv;
            else if (r == 4) m4 = mv; else if (r == 5) m5 = mv;
            else if (r == 6) m6 = mv; else m7 = mv;
        }
    }

    for (int s = 0; s < STEPS; ++s) {
        const int p = s & 1;
        if (G < GROUPS - 1) { st8(&A[p][G][sw], m6); st8(&A[p][G][128 + sw], m7); }
        if (G > 0)          { st8(&B[p][G][sw], m0); st8(&B[p][G][128 + sw], m1); }
        __syncthreads();                              // the ONLY barrier/step
        const uint32_t* cgR = p ? cg0 : cg1;
        uint32_t*       cgW = p ? cg1 : cg0;
        uint32_t fexit = *pR;
        uint32_t act   = cgR[G] | cgR[G + 1] | cgR[G + 2];
        if (s > 0 && fexit == 0) break;               // uniform, exact
        uint32_t cbit;
        if (__any(act != 0)) {
            W8 ha0, ha1, hb0, hb1;
            if (G > 0) { ha0 = ld8(&A[p][G-1][sw]); ha1 = ld8(&A[p][G-1][128+sw]); }
            else       { ha0 = wneg(); ha1 = wneg(); }
            if (G < GROUPS - 1) { hb0 = ld8(&B[p][G+1][sw]); hb1 = ld8(&B[p][G+1][128+sw]); }
            else                { hb0 = wneg(); hb1 = wneg(); }
            // gen t+1 on rows -1..8 (10 rows)
            W8 qa = hpass(wmax(wmax(ha0, ha1), m0), ka);   // row -1
            W8 q0 = hpass(wmax(wmax(ha1, m0), m1), k0);
            W8 q1 = hpass(wmax(wmax(m0, m1), m2), k1);
            W8 q2 = hpass(wmax(wmax(m1, m2), m3), k2);
            W8 q3 = hpass(wmax(wmax(m2, m3), m4), k3);
            W8 q4 = hpass(wmax(wmax(m3, m4), m5), k4);
            W8 q5 = hpass(wmax(wmax(m4, m5), m6), k5);
            W8 q6 = hpass(wmax(wmax(m5, m6), m7), k6);
            W8 q7 = hpass(wmax(wmax(m6, m7), hb0), k7);
            W8 qb = hpass(wmax(wmax(m7, hb0), hb1), kb);   // row 8
            // gen t+2 on owned rows
            W8 n0 = hpass(wmax(wmax(qa, q0), q1), k0);
            W8 n1 = hpass(wmax(wmax(q0, q1), q2), k1);
            W8 n2 = hpass(wmax(wmax(q1, q2), q3), k2);
            W8 n3 = hpass(wmax(wmax(q2, q3), q4), k3);
            W8 n4 = hpass(wmax(wmax(q3, q4), q5), k4);
            W8 n5 = hpass(wmax(wmax(q4, q5), q6), k5);
            W8 n6 = hpass(wmax(wmax(q5, q6), q7), k6);
            W8 n7 = hpass(wmax(wmax(q6, q7), qb), k7);
            uint32_t ch = wdiff(n0, m0) | wdiff(n1, m1) | wdiff(n2, m2) |
                          wdiff(n3, m3) | wdiff(n4, m4) | wdiff(n5, m5) |
                          wdiff(n6, m6) | wdiff(n7, m7);
            uint32_t c = ch;                   // OR across the 16-lane group
            c |= __shfl_xor(c, 1); c |= __shfl_xor(c, 2);
            c |= __shfl_xor(c, 4); c |= __shfl_xor(c, 8);
            cbit = c ? 1u : 0u;
            if (seg == 0) {
                cgW[G + 1] = cbit;             // single writer/group
                if (cbit) *pW = 1;
            }
            m0 = n0; m1 = n1; m2 = n2; m3 = n3;
            m4 = n4; m5 = n5; m6 = n6; m7 = n7;
        } else {
            cbit = 0;
            if (seg == 0) cgW[G + 1] = 0;      // state provably unchanged
        }
        if (tid == 0) *pZ = 0;                 // slot (s+1)%3
        uint32_t* tp = pW; pW = pZ; pZ = pR; pR = tp;   // rotate slots
    }

    // write back all 8 rows as f32
    {
        const size_t ob = ((size_t)b << 16) + ((size_t)(8 * G) << 8) + seg * 16;
        #pragma unroll
        for (int r = 0; r < 8; ++r) {
            W8 mv = (r == 0) ? m0 : (r == 1) ? m1 : (r == 2) ? m2 :
                    (r == 3) ? m3 : (r == 4) ? m4 : (r == 5) ? m5 :
                    (r == 6) ? m6 : m7;
            float* orow = fout + ob + ((size_t)r << 8);
            h2 x, y; float4 f;
            x = __builtin_bit_cast(h2, mv.s0); y = __builtin_bit_cast(h2, mv.s1);
            f.x = (float)x.x; f.y = (float)x.y; f.z = (float)y.x; f.w = (float)y.y;
            reinterpret_cast<float4*>(orow)[0] = f;
            x = __builtin_bit_cast(h2, mv.s2); y = __builtin_bit_cast(h2, mv.s3);
            f.x = (float)x.x; f.y = (float)x.y; f.z = (float)y.x; f.w = (float)y.y;
            reinterpret_cast<float4*>(orow)[1] = f;
            x = __builtin_bit_cast(h2, mv.s4); y = __builtin_bit_cast(h2, mv.s5);
            f.x = (float)x.x; f.y = (float)x.y; f.z = (float)y.x; f.w = (float)y.y;
            reinterpret_cast<float4*>(orow)[2] = f;
            x = __builtin_bit_cast(h2, mv.s6); y = __builtin_bit_cast(h2, mv.s7);
            f.x = (float)x.x; f.y = (float)x.y; f.z = (float)y.x; f.w = (float)y.y;
            reinterpret_cast<float4*>(orow)[3] = f;
        }
    }
}

extern "C" void kernel_launch(void* const* d_in, const int* in_sizes, int n_in,
                              void* d_out, int out_size, void* d_ws, size_t ws_size,
                              hipStream_t stream) {
    const float* img = (const float*)d_in[0];
    const float* hh  = (const float*)d_in[1];
    hx_full<<<128, 512, 0, stream>>>(img, hh, (float*)d_out);
}

// Round 30
// 123.328 us; speedup vs baseline: 1.1345x; 1.1345x over previous
//
#include <hip/hip_runtime.h>
#include <stdint.h>

// H-maxima: 128 iters of m = min(dilate3x3(m), img), marker0 = img - h.
// SINGLE LAUNCH (R24): one block per image (128 blk x 1024 thr), 64 groups x
// 4 rows/thread, all 256 rows in registers. 1 barrier/iter parity halo
// (A/B [2][64][128] = 128 KiB); exit flags in dead rows (3-slot rotation);
// per-group activity skip via chg bitmaps (R25, exact). Store-skip dropped
// (R27: neutral); 2-gen/barrier rejected (R29: +13%, compute ratio).
// R28-FINAL: merged flag+activity loads (one LDS round-trip/iter) and
// seg0-only exit-flag writes. Best measured: 123.4 us.

#define NEGPAIR 0xFBFFFBFFu   // fp16 -65504 x2 == -inf pad
#define TITER 128
#define GROUPS 64

typedef _Float16 h2  __attribute__((ext_vector_type(2)));
typedef __fp16   fh2 __attribute__((ext_vector_type(2)));

static __device__ __forceinline__ uint32_t pmax(uint32_t a, uint32_t b) {
    uint32_t r;
    asm("v_pk_max_f16 %0, %1, %2" : "=v"(r) : "v"(a), "v"(b));
    return r;
}
static __device__ __forceinline__ uint32_t pmin(uint32_t a, uint32_t b) {
    uint32_t r;
    asm("v_pk_min_f16 %0, %1, %2" : "=v"(r) : "v"(a), "v"(b));
    return r;
}
static __device__ __forceinline__ uint32_t alignb(uint32_t hi, uint32_t lo) {
    return __builtin_amdgcn_alignbit(hi, lo, 16);   // {lo.hi16, hi.lo16}
}
static __device__ __forceinline__ uint32_t pack2(float lo, float hi) {
    fh2 p = __builtin_amdgcn_cvt_pkrtz(lo, hi);
    return __builtin_bit_cast(uint32_t, p);
}
// seg s gets seg s-1's word; seg 0 gets NEGPAIR (16-lane DPP row == seg group)
static __device__ __forceinline__ uint32_t dpp_shr1(uint32_t s) {
    return (uint32_t)__builtin_amdgcn_update_dpp((int)NEGPAIR, (int)s, 0x111, 0xF, 0xF, false);
}
// seg s gets seg s+1's word; seg 15 gets NEGPAIR
static __device__ __forceinline__ uint32_t dpp_shl1(uint32_t s) {
    return (uint32_t)__builtin_amdgcn_update_dpp((int)NEGPAIR, (int)s, 0x101, 0xF, 0xF, false);
}

struct W8 { uint32_t s0, s1, s2, s3, s4, s5, s6, s7; };

static __device__ __forceinline__ W8 ld8(const uint32_t* p) {
    uint4 a = reinterpret_cast<const uint4*>(p)[0];
    uint4 b = reinterpret_cast<const uint4*>(p)[1];
    W8 w;
    w.s0 = a.x; w.s1 = a.y; w.s2 = a.z; w.s3 = a.w;
    w.s4 = b.x; w.s5 = b.y; w.s6 = b.z; w.s7 = b.w;
    return w;
}
static __device__ __forceinline__ void st8(uint32_t* p, W8 w) {
    reinterpret_cast<uint4*>(p)[0] = make_uint4(w.s0, w.s1, w.s2, w.s3);
    reinterpret_cast<uint4*>(p)[1] = make_uint4(w.s4, w.s5, w.s6, w.s7);
}
static __device__ __forceinline__ W8 wmax(W8 a, W8 b) {
    W8 r;
    r.s0 = pmax(a.s0, b.s0); r.s1 = pmax(a.s1, b.s1);
    r.s2 = pmax(a.s2, b.s2); r.s3 = pmax(a.s3, b.s3);
    r.s4 = pmax(a.s4, b.s4); r.s5 = pmax(a.s5, b.s5);
    r.s6 = pmax(a.s6, b.s6); r.s7 = pmax(a.s7, b.s7);
    return r;
}
static __device__ __forceinline__ W8 wneg() {
    W8 r;
    r.s0 = NEGPAIR; r.s1 = NEGPAIR; r.s2 = NEGPAIR; r.s3 = NEGPAIR;
    r.s4 = NEGPAIR; r.s5 = NEGPAIR; r.s6 = NEGPAIR; r.s7 = NEGPAIR;
    return r;
}
static __device__ __forceinline__ uint32_t wdiff(W8 a, W8 b) {
    return (a.s0 ^ b.s0) | (a.s1 ^ b.s1) | (a.s2 ^ b.s2) | (a.s3 ^ b.s3) |
           (a.s4 ^ b.s4) | (a.s5 ^ b.s5) | (a.s6 ^ b.s6) | (a.s7 ^ b.s7);
}

// horizontal 3-tap max on packed row v, clamped by k: min(hmax3(v), k)
static __device__ __forceinline__ W8 hpass(W8 v, W8 k) {
    uint32_t lv = dpp_shr1(v.s7);
    uint32_t rv = dpp_shl1(v.s0);
    W8 m;
    m.s0 = pmin(pmax(pmax(v.s0, alignb(v.s0, lv)),   alignb(v.s1, v.s0)), k.s0);
    m.s1 = pmin(pmax(pmax(v.s1, alignb(v.s1, v.s0)), alignb(v.s2, v.s1)), k.s1);
    m.s2 = pmin(pmax(pmax(v.s2, alignb(v.s2, v.s1)), alignb(v.s3, v.s2)), k.s2);
    m.s3 = pmin(pmax(pmax(v.s3, alignb(v.s3, v.s2)), alignb(v.s4, v.s3)), k.s3);
    m.s4 = pmin(pmax(pmax(v.s4, alignb(v.s4, v.s3)), alignb(v.s5, v.s4)), k.s4);
    m.s5 = pmin(pmax(pmax(v.s5, alignb(v.s5, v.s4)), alignb(v.s6, v.s5)), k.s5);
    m.s6 = pmin(pmax(pmax(v.s6, alignb(v.s6, v.s5)), alignb(v.s7, v.s6)), k.s6);
    m.s7 = pmin(pmax(pmax(v.s7, alignb(v.s7, v.s6)), alignb(rv,   v.s7)), k.s7);
    return m;
}

__global__ __launch_bounds__(1024, 1) void hx_full(
    const float* __restrict__ img,   // f32 [128][256][256]
    const float* __restrict__ hh,    // f32 [128]
    float*       __restrict__ fout)  // f32 out
{
    // Parity halo-row buffers. A[p][g] = g's bottom row (read by g+1);
    // B[p][g] = g's top row (read by g-1). Dead rows B[p][0], A[p][63] host
    // the 3 exit-flag slots (word 0) and the chg bitmaps (A[p][63][8..73]).
    __shared__ uint32_t A[2][GROUPS][128];   // 65,536 B
    __shared__ uint32_t B[2][GROUPS][128];   // 65,536 B (total exactly 128 KiB)

    const int tid = threadIdx.x;
    const int seg = tid & 15;
    const int g   = tid >> 4;        // 64 groups x 4 rows = 256 rows
    const int b   = blockIdx.x;      // one image per block
    const int sw  = seg * 8;

    uint32_t* f0p = &B[0][0][0];
    uint32_t* f1p = &B[1][0][0];
    uint32_t* f2p = &A[0][GROUPS - 1][0];
    uint32_t* cg0 = &A[0][GROUPS - 1][8];   // chg parity 0: entries [0..65]
    uint32_t* cg1 = &A[1][GROUPS - 1][8];   // chg parity 1
    if (tid == 0) { *f0p = 0; *f1p = 0; *f2p = 0; }
    if (tid < 66) {                         // pad entries 0,65 = 0; groups = 1
        uint32_t v = (tid >= 1 && tid <= 64) ? 1u : 0u;
        cg0[tid] = v; cg1[tid] = v;
    }
    uint32_t *pW = f0p, *pR = f2p, *pZ = f1p;  // t=0: write s0, read s2, reset s1

    // Fused init: rows 4g..4g+3 always in [0,256) -- no bounds checks.
    W8 m0, m1, m2, m3, k0, k1, k2, k3;
    const float hb = hh[b];
    {
        const size_t ib = ((size_t)b << 16) + ((size_t)(4 * g) << 8) + seg * 16;
        #pragma unroll
        for (int r = 0; r < 4; ++r) {
            const float4* src = reinterpret_cast<const float4*>(img + ib + ((size_t)r << 8));
            float4 fa = src[0], fb = src[1], fc = src[2], fd = src[3];
            W8 kv, mv;
            kv.s0 = pack2(fa.x, fa.y);       kv.s1 = pack2(fa.z, fa.w);
            kv.s2 = pack2(fb.x, fb.y);       kv.s3 = pack2(fb.z, fb.w);
            kv.s4 = pack2(fc.x, fc.y);       kv.s5 = pack2(fc.z, fc.w);
            kv.s6 = pack2(fd.x, fd.y);       kv.s7 = pack2(fd.z, fd.w);
            mv.s0 = pack2(fa.x-hb, fa.y-hb); mv.s1 = pack2(fa.z-hb, fa.w-hb);
            mv.s2 = pack2(fb.x-hb, fb.y-hb); mv.s3 = pack2(fb.z-hb, fb.w-hb);
            mv.s4 = pack2(fc.x-hb, fc.y-hb); mv.s5 = pack2(fc.z-hb, fc.w-hb);
            mv.s6 = pack2(fd.x-hb, fd.y-hb); mv.s7 = pack2(fd.z-hb, fd.w-hb);
            if (r == 0) { m0 = mv; k0 = kv; }
            else if (r == 1) { m1 = mv; k1 = kv; }
            else if (r == 2) { m2 = mv; k2 = kv; }
            else { m3 = mv; k3 = kv; }
        }
    }

    for (int t = 0; t < TITER; ++t) {
        const int p = t & 1;
        if (g < GROUPS - 1) st8(&A[p][g][sw], m3);
        if (g > 0)          st8(&B[p][g][sw], m0);
        __syncthreads();                              // the ONLY barrier/iter
        // merged loads: flag + activity issued together; chg latency
        // overlaps the flag wait/branch.
        const uint32_t* cgR = p ? cg0 : cg1;   // gen-t changes (written iter t-1)
        uint32_t*       cgW = p ? cg1 : cg0;   // gen-(t+1) changes (read iter t+1)
        uint32_t fexit = *pR;
        uint32_t act   = cgR[g] | cgR[g + 1] | cgR[g + 2];
        if (t > 0 && fexit == 0) break;               // uniform, exact
        uint32_t cbit;
        if (__any(act != 0)) {
            W8 ab = (g > 0)          ? ld8(&A[p][g - 1][sw]) : wneg();
            W8 bl = (g < GROUPS - 1) ? ld8(&B[p][g + 1][sw]) : wneg();
            W8 t01 = wmax(m0, m1);
            W8 t12 = wmax(m1, m2);
            W8 t23 = wmax(m2, m3);
            W8 nm1 = hpass(wmax(t01, m2), k1);
            W8 nm2 = hpass(wmax(t12, m3), k2);
            W8 v0  = wmax(ab, t01);
            W8 v3  = wmax(t23, bl);
            W8 nm0 = hpass(v0, k0);
            W8 nm3 = hpass(v3, k3);
            uint32_t ch = wdiff(nm0, m0) | wdiff(nm1, m1) |
                          wdiff(nm2, m2) | wdiff(nm3, m3);
            uint32_t c = ch;                   // OR across the 16-lane group
            c |= __shfl_xor(c, 1); c |= __shfl_xor(c, 2);
            c |= __shfl_xor(c, 4); c |= __shfl_xor(c, 8);
            cbit = c ? 1u : 0u;
            if (seg == 0) {
                cgW[g + 1] = cbit;             // single writer/group
                if (cbit) *pW = 1;             // <=4 lanes/wave same-addr write
            }
            m0 = nm0; m1 = nm1; m2 = nm2; m3 = nm3;
        } else {
            cbit = 0;
            if (seg == 0) cgW[g + 1] = 0;      // state provably unchanged
        }
        if (tid == 0) *pZ = 0;                 // slot (t+1)%3
        uint32_t* tp = pW; pW = pZ; pZ = pR; pR = tp;   // rotate slots
    }

    // write back all 4 rows as f32
    {
        const size_t ob = ((size_t)b << 16) + ((size_t)(4 * g) << 8) + seg * 16;
        #pragma unroll
        for (int r = 0; r < 4; ++r) {
            W8 mv = (r == 0) ? m0 : (r == 1) ? m1 : (r == 2) ? m2 : m3;
            float* orow = fout + ob + ((size_t)r << 8);
            h2 x, y; float4 f;
            x = __builtin_bit_cast(h2, mv.s0); y = __builtin_bit_cast(h2, mv.s1);
            f.x = (float)x.x; f.y = (float)x.y; f.z = (float)y.x; f.w = (float)y.y;
            reinterpret_cast<float4*>(orow)[0] = f;
            x = __builtin_bit_cast(h2, mv.s2); y = __builtin_bit_cast(h2, mv.s3);
            f.x = (float)x.x; f.y = (float)x.y; f.z = (float)y.x; f.w = (float)y.y;
            reinterpret_cast<float4*>(orow)[1] = f;
            x = __builtin_bit_cast(h2, mv.s4); y = __builtin_bit_cast(h2, mv.s5);
            f.x = (float)x.x; f.y = (float)x.y; f.z = (float)y.x; f.w = (float)y.y;
            reinterpret_cast<float4*>(orow)[2] = f;
            x = __builtin_bit_cast(h2, mv.s6); y = __builtin_bit_cast(h2, mv.s7);
            f.x = (float)x.x; f.y = (float)x.y; f.z = (float)y.x; f.w = (float)y.y;
            reinterpret_cast<float4*>(orow)[3] = f;
        }
    }
}

extern "C" void kernel_launch(void* const* d_in, const int* in_sizes, int n_in,
                              void* d_out, int out_size, void* d_ws, size_t ws_size,
                              hipStream_t stream) {
    const float* img = (const float*)d_in[0];
    const float* hh  = (const float*)d_in[1];
    hx_full<<<128, 1024, 0, stream>>>(img, hh, (float*)d_out);
}